// Round 13
// baseline (644.027 us; speedup 1.0000x reference)
//
#include <hip/hip_runtime.h>
#include <math.h>

#define NN 50000
#define MM 800000
#define HH 64
#define NB_EDGE 1792
#define NTILE 12500                 // MM / 64 edges per block-tile
#define BSH 13                      // col bucket shift (8192 cols = 1MB hb)
#define NBUK 7                      // ceil(50000 / 8192)
#define NKEY 350000                 // NBUK * NN
#define NCHK 1400                   // NKEY / 250 scan chunks

typedef short bf16x8 __attribute__((ext_vector_type(8)));
typedef float f32x4  __attribute__((ext_vector_type(4)));

// per-wave LDS fence: all LDS regions are wave-private; lockstep + lgkmcnt
// drain replaces __syncthreads
#define WFENCE() asm volatile("s_waitcnt lgkmcnt(0)" ::: "memory")

__device__ __forceinline__ float silu_f(float v) {
    return v * __builtin_amdgcn_rcpf(1.0f + __expf(-v));
}
// round-half-up fp32 -> bf16 bits (0.5 ulp max)
__device__ __forceinline__ unsigned short bfb(float a) {
    return (unsigned short)((__float_as_uint(a) + 0x8000u) >> 16);
}
// pack two f32 -> bf16x2 via v_perm (low = a, high = b)
__device__ __forceinline__ unsigned pk2(float a, float b) {
    return __builtin_amdgcn_perm(__float_as_uint(b) + 0x8000u,
                                 __float_as_uint(a) + 0x8000u, 0x07060302u);
}
__device__ __forceinline__ float b2f(unsigned short s) {
    return __uint_as_float((unsigned)s << 16);
}
// packed bf16x2 atomic add
__device__ __forceinline__ void atomic_pk_bf16(unsigned short* addr, unsigned pk) {
    asm volatile("global_atomic_pk_add_bf16 %0, %1, off"
                 :: "v"((unsigned long long)(size_t)addr), "v"(pk) : "memory");
}

// ---------------- fused setup: hist + weight-swizzle + embed + zero + xcopy --
// blocks [0,3125): deg/key histograms
// blocks [3125,3365): weight pre-swizzle (per layer 30720 shorts)
// blocks [3365,15865): embedding
// blocks [15865,17574): zero sum_f+tmsgb (7,000,000 B)
// blocks [17574,17721): copy x_in -> xo
__global__ __launch_bounds__(256) void setup_kernel(
    const int* __restrict__ row, const int* __restrict__ col,
    int* __restrict__ deg, int* __restrict__ kcnt,
    const float* __restrict__ eW1, const float* __restrict__ eW2,
    const float* __restrict__ cW1, const float* __restrict__ nW1,
    const float* __restrict__ nW2, unsigned short* __restrict__ wsW,
    const float* __restrict__ h_in, const float* __restrict__ emb_W,
    const float* __restrict__ emb_b, float* __restrict__ h_out,
    unsigned short* __restrict__ hb,
    char* __restrict__ zbase, const float* __restrict__ x_in,
    float* __restrict__ xo)
{
    const int b = blockIdx.x;
    if (b < 3125) {
        const int e = b * 256 + threadIdx.x;
        const int r = row[e], c = col[e];
        atomicAdd(&deg[r], 1);
        atomicAdd(&kcnt[(c >> BSH) * NN + r], 1);
    } else if (b < 3365) {
        const int i = (b - 3125) * 256 + threadIdx.x;     // 0 .. 61439
        const int layer = i / 30720;
        const int rem = i - layer * 30720;
        float val;
        if (rem < 10240) {
            const int j = rem & 7, lane = (rem >> 3) & 63, nt = (rem >> 9) & 3, s = rem >> 11;
            const int kp = s * 32 + ((lane >> 4) << 3) + j;
            const int n  = nt * 16 + (lane & 15);
            if (kp > 136) val = 0.0f;
            else {
                const int k = (kp == 136) ? 0 : kp + 1;   // k'=136 is the r2 row
                val = eW1[layer * 137 * 64 + k * 64 + n];
            }
        } else if (rem < 14336) {
            const int r2 = rem - 10240;
            const int j = r2 & 7, lane = (r2 >> 3) & 63, nt = (r2 >> 9) & 3, s = r2 >> 11;
            val = eW2[layer * 4096 + (s * 32 + ((lane >> 4) << 3) + j) * 64 + nt * 16 + (lane & 15)];
        } else if (rem < 18432) {
            const int r3 = rem - 14336;
            const int j = r3 & 7, lane = (r3 >> 3) & 63, nt = (r3 >> 9) & 3, s = r3 >> 11;
            val = cW1[layer * 4096 + (s * 32 + ((lane >> 4) << 3) + j) * 64 + nt * 16 + (lane & 15)];
        } else if (rem < 26624) {
            const int r4 = rem - 18432;
            const int j = r4 & 7, lane = (r4 >> 3) & 63, nt = (r4 >> 9) & 3, s = r4 >> 11;
            const int kp = s * 32 + ((lane >> 4) << 3) + j;      // < 128
            val = nW1[layer * 8192 + kp * 64 + nt * 16 + (lane & 15)];
        } else {
            const int r5 = rem - 26624;
            const int j = r5 & 7, lane = (r5 >> 3) & 63, nt = (r5 >> 9) & 3, s = r5 >> 11;
            val = nW2[layer * 4096 + (s * 32 + ((lane >> 4) << 3) + j) * 64 + nt * 16 + (lane & 15)];
        }
        wsW[i] = bfb(val);
    } else if (b < 15865) {
        const int idx = (b - 3365) * 256 + threadIdx.x;   // over N*64
        const int n = idx >> 6, j = idx & 63;
        float acc = emb_b[j];
        #pragma unroll
        for (int k = 0; k < 16; ++k)
            acc += h_in[n * 16 + k] * emb_W[k * HH + j];
        h_out[idx] = acc;
        hb[idx] = bfb(acc);
    } else if (b < 17574) {
        const int t = (b - 15865) * 256 + threadIdx.x;
        if (t < 437500) {                                  // 7,000,000 / 16
            const uint4 z = {0u, 0u, 0u, 0u};
            *(uint4*)(zbase + (size_t)t * 16) = z;
        }
    } else {
        const int t = (b - 17574) * 256 + threadIdx.x;
        if (t < 37500)                                     // N*3 floats / 4
            ((uint4*)xo)[t] = ((const uint4*)x_in)[t];
    }
}

// parallel scan over NKEY, phase A: NCHK blocks x 250-key chunks -> blocksum
__global__ __launch_bounds__(256) void scanA_kernel(const int* __restrict__ kcnt,
                                                    int* __restrict__ bsum) {
    __shared__ int ps[256];
    const int t = threadIdx.x;
    const int base = blockIdx.x * 250;
    int v = (t < 250) ? kcnt[base + t] : 0;
    ps[t] = v;
    __syncthreads();
    for (int off = 1; off < 256; off <<= 1) {
        const int u = (t >= off) ? ps[t - off] : 0;
        __syncthreads();
        ps[t] += u;
        __syncthreads();
    }
    if (t == 255) bsum[blockIdx.x] = ps[255];
}

// phase B: exclusive scan of NCHK blocksums (1024 threads, 2 per thread)
__global__ __launch_bounds__(1024) void scanB_kernel(const int* __restrict__ bsum,
                                                     int* __restrict__ boff) {
    __shared__ int ps[1024];
    const int t = threadIdx.x;
    const int e0 = 2 * t, e1 = 2 * t + 1;
    const int v0 = (e0 < NCHK) ? bsum[e0] : 0;
    const int v1 = (e1 < NCHK) ? bsum[e1] : 0;
    const int pair = v0 + v1;
    ps[t] = pair;
    __syncthreads();
    for (int off = 1; off < 1024; off <<= 1) {
        const int u = (t >= off) ? ps[t - off] : 0;
        __syncthreads();
        ps[t] += u;
        __syncthreads();
    }
    const int excl = ps[t] - pair;
    if (e0 < NCHK) boff[e0] = excl;
    if (e1 < NCHK) boff[e1] = excl + v0;
}

// phase C: per-chunk exclusive scan + global offset -> kcur
__global__ __launch_bounds__(256) void scanC_kernel(const int* __restrict__ kcnt,
                                                    const int* __restrict__ boff,
                                                    int* __restrict__ kcur) {
    __shared__ int ps[256];
    const int t = threadIdx.x;
    const int base = blockIdx.x * 250;
    int v = (t < 250) ? kcnt[base + t] : 0;
    ps[t] = v;
    __syncthreads();
    for (int off = 1; off < 256; off <<= 1) {
        const int u = (t >= off) ? ps[t - off] : 0;
        __syncthreads();
        ps[t] += u;
        __syncthreads();
    }
    if (t < 250)
        kcur[base + t] = boff[blockIdx.x] + ps[t] - v;   // exclusive prefix
}

// counting-sort fill by key=(col>>BSH)*NN+row: bucket-major, row-minor
__global__ __launch_bounds__(256) void fill_kernel(
    const int* __restrict__ row, const int* __restrict__ col,
    const float* __restrict__ efea, int* __restrict__ kcur,
    int* __restrict__ rs, int* __restrict__ cs, unsigned short* __restrict__ efs)
{
    const int e = blockIdx.x * 256 + threadIdx.x;
    const int r = row[e], c = col[e];
    const int pos = atomicAdd(&kcur[(c >> BSH) * NN + r], 1);
    rs[pos] = r;
    cs[pos] = c;
    const float4* ef = (const float4*)(efea + (size_t)e * 8);
    const float4 e0 = ef[0], e1 = ef[1];
    uint4 ue = { pk2(e0.x, e0.y), pk2(e0.z, e0.w), pk2(e1.x, e1.y), pk2(e1.z, e1.w) };
    *(uint4*)(efs + (size_t)pos * 8) = ue;
}

// ---------------- MFMA edge kernel: 16 sorted edges per wave ----------------
// Edges sorted by (col-bucket, row): col gathers are L2-resident per bucket
// sweep; rows sorted within bucket -> segmented flush still applies.
__global__ __launch_bounds__(256, 7) void edge_mfma_kernel(
    const float* __restrict__ x, const unsigned short* __restrict__ hb,
    const int* __restrict__ rs, const int* __restrict__ cs,
    const unsigned short* __restrict__ efs,
    const unsigned short* __restrict__ w1b, const unsigned short* __restrict__ w2b,
    const unsigned short* __restrict__ cw1b,
    const float* __restrict__ b1, const float* __restrict__ b2,
    const float* __restrict__ cb1, const float* __restrict__ cw2,
    const float* __restrict__ cb2,
    float* __restrict__ sum_f, unsigned short* __restrict__ tmsgb)
{
    __shared__ __align__(16) unsigned short S[4][16][168];
    __shared__ float RV[4][16][4];
    __shared__ int   RI[4][16];

    const int tid = threadIdx.x;
    const int w = tid >> 6, lane = tid & 63;
    const int l15 = lane & 15, quad = lane >> 4;
    const int le = lane >> 2, sub = lane & 3;

    float b1v[4], b2v[4], cb1v[4], cw2v[4];
    #pragma unroll
    for (int nt = 0; nt < 4; ++nt) {
        b1v[nt]  = b1[nt * 16 + l15];
        b2v[nt]  = b2[nt * 16 + l15];
        cb1v[nt] = cb1[nt * 16 + l15];
        cw2v[nt] = cw2[nt * 16 + l15];
    }
    const float cb2s = cb2[0];

    {   // zero the K-pad [138,160) once; never overwritten afterwards
        unsigned short* Sr = &S[w][le][0];
        if (sub == 0) {
            *(unsigned*)&Sr[138] = 0u; *(unsigned*)&Sr[140] = 0u; *(unsigned*)&Sr[142] = 0u;
        } else if (sub == 1) {
            *(unsigned*)&Sr[144] = 0u; *(unsigned*)&Sr[146] = 0u;
            *(unsigned*)&Sr[148] = 0u; *(unsigned*)&Sr[150] = 0u;
        } else if (sub == 2) {
            *(unsigned*)&Sr[152] = 0u; *(unsigned*)&Sr[154] = 0u;
            *(unsigned*)&Sr[156] = 0u; *(unsigned*)&Sr[158] = 0u;
        }
    }
    WFENCE();

    for (int bt = blockIdx.x; bt < NTILE; bt += NB_EDGE) {
        const int t = bt * 4 + w;
        const int p = t * 16 + le;           // sorted edge position
        const int r = rs[p], c = cs[p];

        // ---- gather: 4 lanes per edge, bf16 uint4 copies ----
        unsigned short* Srow = &S[w][le][0];
        {
            const unsigned short* hr = hb + (size_t)r * HH + sub * 16;
            uint4 u0 = *(const uint4*)(hr);
            uint4 u1 = *(const uint4*)(hr + 8);
            *(uint4*)&Srow[sub * 16]     = u0;
            *(uint4*)&Srow[sub * 16 + 8] = u1;
            const unsigned short* hc = hb + (size_t)c * HH + sub * 16;
            uint4 v0 = *(const uint4*)(hc);
            uint4 v1 = *(const uint4*)(hc + 8);
            *(uint4*)&Srow[64 + sub * 16]     = v0;
            *(uint4*)&Srow[64 + sub * 16 + 8] = v1;
        }
        if (sub == 0) {
            const float rx = x[3 * r + 0] - x[3 * c + 0];
            const float ry = x[3 * r + 1] - x[3 * c + 1];
            const float rz = x[3 * r + 2] - x[3 * c + 2];
            const float r2 = rx * rx + ry * ry + rz * rz;
            RV[w][le][0] = rx; RV[w][le][1] = ry; RV[w][le][2] = rz;
            RI[w][le] = r;
            *(unsigned*)&Srow[136] = (unsigned)bfb(r2);   // zeroes col 137 too
        } else if (sub == 1) {
            *(uint4*)&Srow[128] = *(const uint4*)(efs + (size_t)p * 8);
        }
        WFENCE();

        // ---- GEMM1: S[16x160] @ W1[160x64] -> H1 (alias cols 0..63) ----
        bf16x8 af[5];
        #pragma unroll
        for (int s = 0; s < 5; ++s)
            af[s] = *(const bf16x8*)&S[w][l15][s * 32 + quad * 8];
        WFENCE();   // af in regs before H1 overwrites the same cols
        #pragma unroll
        for (int nt = 0; nt < 4; ++nt) {
            f32x4 a = {0.f, 0.f, 0.f, 0.f};
            #pragma unroll
            for (int s = 0; s < 5; ++s) {
                bf16x8 bf = *(const bf16x8*)(w1b + ((s * 4 + nt) * 64 + lane) * 8);
                a = __builtin_amdgcn_mfma_f32_16x16x32_bf16(af[s], bf, a, 0, 0, 0);
            }
            #pragma unroll
            for (int rr = 0; rr < 4; ++rr)
                S[w][quad * 4 + rr][nt * 16 + l15] = bfb(silu_f(a[rr] + b1v[nt]));
        }
        WFENCE();

        // ---- GEMM2: H1 @ W2 -> msg (alias back into cols 0..63) ----
        bf16x8 a2[2];
        #pragma unroll
        for (int s = 0; s < 2; ++s)
            a2[s] = *(const bf16x8*)&S[w][l15][s * 32 + quad * 8];
        WFENCE();   // a2 in regs before MS overwrites
        #pragma unroll
        for (int nt = 0; nt < 4; ++nt) {
            f32x4 m = {0.f, 0.f, 0.f, 0.f};
            #pragma unroll
            for (int s = 0; s < 2; ++s) {
                bf16x8 bf = *(const bf16x8*)(w2b + ((s * 4 + nt) * 64 + lane) * 8);
                m = __builtin_amdgcn_mfma_f32_16x16x32_bf16(a2[s], bf, m, 0, 0, 0);
            }
            #pragma unroll
            for (int rr = 0; rr < 4; ++rr)
                S[w][quad * 4 + rr][nt * 16 + l15] = bfb(silu_f(m[rr] + b2v[nt]));
        }
        WFENCE();

        // ---- GEMM3: msg @ cW1 -> c1; dot cW2 -> cm (cols 160..162) ----
        bf16x8 a3[2];
        #pragma unroll
        for (int s = 0; s < 2; ++s)
            a3[s] = *(const bf16x8*)&S[w][l15][s * 32 + quad * 8];
        float pr[4] = {0.f, 0.f, 0.f, 0.f};
        #pragma unroll
        for (int nt = 0; nt < 4; ++nt) {
            f32x4 q = {0.f, 0.f, 0.f, 0.f};
            #pragma unroll
            for (int s = 0; s < 2; ++s) {
                bf16x8 bf = *(const bf16x8*)(cw1b + ((s * 4 + nt) * 64 + lane) * 8);
                q = __builtin_amdgcn_mfma_f32_16x16x32_bf16(a3[s], bf, q, 0, 0, 0);
            }
            #pragma unroll
            for (int rr = 0; rr < 4; ++rr)
                pr[rr] += silu_f(q[rr] + cb1v[nt]) * cw2v[nt];
        }
        #pragma unroll
        for (int rr = 0; rr < 4; ++rr) {
            float tt = pr[rr];
            tt += __shfl_xor(tt, 1, 64);
            tt += __shfl_xor(tt, 2, 64);
            tt += __shfl_xor(tt, 4, 64);
            tt += __shfl_xor(tt, 8, 64);
            if (l15 == 0) *(float*)&S[w][quad * 4 + rr][160] = tt + cb2s;
        }
        WFENCE();

        // ---- segmented flush: rows sorted by RI within the tile ----
        if (lane < 32) {   // msg -> tmsgb: lane owns cols {2l, 2l+1}, pk atomic
            unsigned both = *(const unsigned*)&S[w][0][2 * lane];
            float ax = b2f((unsigned short)(both & 0xffffu));
            float ay = b2f((unsigned short)(both >> 16));
            int cur_r = RI[w][0];
            #pragma unroll
            for (int g = 1; g < 16; ++g) {
                const int ri = RI[w][g];
                unsigned bv = *(const unsigned*)&S[w][g][2 * lane];
                const float vx = b2f((unsigned short)(bv & 0xffffu));
                const float vy = b2f((unsigned short)(bv >> 16));
                if (ri != cur_r) {
                    atomic_pk_bf16(&tmsgb[(size_t)cur_r * HH + 2 * lane], pk2(ax, ay));
                    ax = 0.f; ay = 0.f; cur_r = ri;
                }
                ax += vx; ay += vy;
            }
            atomic_pk_bf16(&tmsgb[(size_t)cur_r * HH + 2 * lane], pk2(ax, ay));
        } else if ((lane & 31) < 3) {   // f = rij*cm -> sum_f (fp32, tiny)
            const int sl = lane & 31;
            float acc = RV[w][0][sl] * (*(const float*)&S[w][0][160]);
            int cur_r = RI[w][0];
            #pragma unroll
            for (int g = 1; g < 16; ++g) {
                const int ri = RI[w][g];
                const float v = RV[w][g][sl] * (*(const float*)&S[w][g][160]);
                if (ri != cur_r) {
                    atomicAdd(&sum_f[3 * cur_r + sl], acc);
                    acc = 0.f; cur_r = ri;
                }
                acc += v;
            }
            atomicAdd(&sum_f[3 * cur_r + sl], acc);
        }
        WFENCE();
    }
}

// ---------------- MFMA node kernel: 16 nodes per wave ----------------
// Reads bf16 tmsgb directly; zeroes tmsgb/sum_f after use (next layer's init).
__global__ __launch_bounds__(256) void node_mfma_kernel(
    float* __restrict__ x, float* __restrict__ h,
    unsigned short* __restrict__ hb,
    float* __restrict__ sum_f, const int* __restrict__ deg,
    unsigned short* __restrict__ tmsgb,
    const unsigned short* __restrict__ nw1b, const unsigned short* __restrict__ nw2b,
    const float* __restrict__ nb1, const float* __restrict__ nb2)
{
    __shared__ __align__(16) unsigned short S[4][16][136];
    const int tid = threadIdx.x;
    const int w = tid >> 6, lane = tid & 63;
    const int l15 = lane & 15, quad = lane >> 4;
    const int le = lane >> 2, sub = lane & 3;
    const int t = blockIdx.x * 4 + w;
    if (t >= NN / 16) return;                      // 3125 waves exactly

    // gather (fully coalesced): [hb | tmsgb] -> S[16][128]; zero tmsgb after
    {
        unsigned short* Srow = &S[w][le][0];
        const int n = t * 16 + le;
        const unsigned short* hr = hb + (size_t)n * HH + sub * 16;
        *(uint4*)&Srow[sub * 16]     = *(const uint4*)(hr);
        *(uint4*)&Srow[sub * 16 + 8] = *(const uint4*)(hr + 8);
        unsigned short* tm = tmsgb + (size_t)n * HH + sub * 16;
        *(uint4*)&Srow[64 + sub * 16]     = *(const uint4*)(tm);
        *(uint4*)&Srow[64 + sub * 16 + 8] = *(const uint4*)(tm + 8);
        const uint4 z = {0u, 0u, 0u, 0u};
        *(uint4*)(tm)     = z;
        *(uint4*)(tm + 8) = z;
    }
    // x update: one lane per node; zero sum_f after
    if (lane < 16) {
        const int nn = t * 16 + lane;
        const float cn = fmaxf((float)deg[nn], 1.0f);
        const float rc = __builtin_amdgcn_rcpf(cn);
        #pragma unroll
        for (int d3 = 0; d3 < 3; ++d3) {
            float tf = sum_f[3 * nn + d3] * rc;
            tf = fminf(fmaxf(tf, -100.0f), 100.0f);
            x[3 * nn + d3] += tf;
            sum_f[3 * nn + d3] = 0.0f;
        }
    }
    WFENCE();

    // GEMM1: [16x128] @ nW1[128x64] -> SiLU -> alias cols 0..63
    bf16x8 af[4];
    #pragma unroll
    for (int s = 0; s < 4; ++s)
        af[s] = *(const bf16x8*)&S[w][l15][s * 32 + quad * 8];
    WFENCE();
    float nb1v[4], nb2v[4];
    #pragma unroll
    for (int nt = 0; nt < 4; ++nt) {
        nb1v[nt] = nb1[nt * 16 + l15];
        nb2v[nt] = nb2[nt * 16 + l15];
    }
    #pragma unroll
    for (int nt = 0; nt < 4; ++nt) {
        f32x4 a = {0.f, 0.f, 0.f, 0.f};
        #pragma unroll
        for (int s = 0; s < 4; ++s) {
            bf16x8 bf = *(const bf16x8*)(nw1b + ((s * 4 + nt) * 64 + lane) * 8);
            a = __builtin_amdgcn_mfma_f32_16x16x32_bf16(af[s], bf, a, 0, 0, 0);
        }
        #pragma unroll
        for (int rr = 0; rr < 4; ++rr)
            S[w][quad * 4 + rr][nt * 16 + l15] = bfb(silu_f(a[rr] + nb1v[nt]));
    }
    WFENCE();

    // GEMM2: [16x64] @ nW2[64x64] -> h (no act)
    bf16x8 a2[2];
    #pragma unroll
    for (int s = 0; s < 2; ++s)
        a2[s] = *(const bf16x8*)&S[w][l15][s * 32 + quad * 8];
    #pragma unroll
    for (int nt = 0; nt < 4; ++nt) {
        f32x4 m = {0.f, 0.f, 0.f, 0.f};
        #pragma unroll
        for (int s = 0; s < 2; ++s) {
            bf16x8 bf = *(const bf16x8*)(nw2b + ((s * 4 + nt) * 64 + lane) * 8);
            m = __builtin_amdgcn_mfma_f32_16x16x32_bf16(a2[s], bf, m, 0, 0, 0);
        }
        #pragma unroll
        for (int rr = 0; rr < 4; ++rr) {
            const float v = m[rr] + nb2v[nt];
            const size_t nd = (size_t)(t * 16 + quad * 4 + rr) * HH + nt * 16 + l15;
            h[nd] = v;
            hb[nd] = bfb(v);
        }
    }
}

extern "C" void kernel_launch(void* const* d_in, const int* in_sizes, int n_in,
                              void* d_out, int out_size, void* d_ws, size_t ws_size,
                              hipStream_t stream) {
    const float* x_in  = (const float*)d_in[0];
    const float* h_in  = (const float*)d_in[1];
    const int*   row   = (const int*)d_in[2];
    const int*   col   = (const int*)d_in[3];
    const float* efea  = (const float*)d_in[4];
    const float* emb_W = (const float*)d_in[5];
    const float* emb_b = (const float*)d_in[6];
    const float* eW1   = (const float*)d_in[7];
    const float* eb1   = (const float*)d_in[8];
    const float* eW2   = (const float*)d_in[9];
    const float* eb2   = (const float*)d_in[10];
    const float* cW1   = (const float*)d_in[11];
    const float* cb1   = (const float*)d_in[12];
    const float* cW2   = (const float*)d_in[13];
    const float* cb2   = (const float*)d_in[14];
    const float* nW1   = (const float*)d_in[15];
    const float* nb1   = (const float*)d_in[16];
    const float* nW2   = (const float*)d_in[17];
    const float* nb2   = (const float*)d_in[18];

    float* out = (float*)d_out;
    float* xo = out;                 // N*3
    float* ho = out + NN * 3;        // N*64

    // workspace layout (16B-aligned segments)
    char* wsb = (char*)d_ws;
    float* sum_f = (float*)wsb;                                  //    600,000 B
    unsigned short* tmsgb = (unsigned short*)(wsb + 600000);     //  6,400,000 B
    unsigned short* efs = (unsigned short*)(wsb + 7000000);      // 12,800,000 B
    unsigned short* hb  = (unsigned short*)(wsb + 19800000);     //  6,400,000 B
    unsigned short* wsW = (unsigned short*)(wsb + 26200000);     //    122,880 B
    int* deg    = (int*)(wsb + 26322880);                        //    200,000 B
    int* kcnt   = (int*)(wsb + 26522880);                        //  1,400,000 B
    int* kcur   = (int*)(wsb + 27922880);                        //  1,400,000 B
    int* rs     = (int*)(wsb + 29322880);                        //  3,200,000 B
    int* cs     = (int*)(wsb + 32522880);                        //  3,200,000 B
    int* bsum   = (int*)(wsb + 35722880);                        //      5,600 B
    int* boff   = (int*)(wsb + 35728480);                        //      5,600 B

    // zero deg + kcnt (contiguous)
    hipMemsetAsync(deg, 0, 1600000, stream);
    // fused: histograms + weight swizzle + embed + zero(sum_f,tmsgb) + x copy
    setup_kernel<<<17721, 256, 0, stream>>>(
        row, col, deg, kcnt,
        eW1, eW2, cW1, nW1, nW2, wsW,
        h_in, emb_W, emb_b, ho, hb,
        wsb, x_in, xo);
    // key scan + bucket-major counting sort
    scanA_kernel<<<NCHK, 256, 0, stream>>>(kcnt, bsum);
    scanB_kernel<<<1, 1024, 0, stream>>>(bsum, boff);
    scanC_kernel<<<NCHK, 256, 0, stream>>>(kcnt, boff, kcur);
    fill_kernel<<<MM / 256, 256, 0, stream>>>(row, col, efea, kcur, rs, cs, efs);

    for (int i = 0; i < 2; ++i) {
        const unsigned short* L = wsW + i * 30720;
        edge_mfma_kernel<<<NB_EDGE, 256, 0, stream>>>(
            xo, hb, rs, cs, efs,
            L, L + 10240, L + 14336,
            eb1 + i * 64, eb2 + i * 64, cb1 + i * 64, cW2 + i * 64, cb2 + i,
            sum_f, tmsgb);
        node_mfma_kernel<<<(NN / 16 + 3) / 4, 256, 0, stream>>>(
            xo, ho, hb, sum_f, deg, tmsgb,
            L + 18432, L + 26624, nb1 + i * 64, nb2 + i * 64);
    }
}

// Round 14
// 602.431 us; speedup vs baseline: 1.0690x; 1.0690x over previous
//
#include <hip/hip_runtime.h>
#include <math.h>

#define NN 50000
#define MM 800000
#define HH 64
#define NB_EDGE 1792
#define NTILE 12500                 // MM / 64 edges per block-tile

typedef short bf16x8 __attribute__((ext_vector_type(8)));
typedef float f32x4  __attribute__((ext_vector_type(4)));

// per-wave LDS fence: all LDS regions are wave-private; lockstep + lgkmcnt
// drain replaces __syncthreads
#define WFENCE() asm volatile("s_waitcnt lgkmcnt(0)" ::: "memory")

__device__ __forceinline__ float silu_f(float v) {
    return v * __builtin_amdgcn_rcpf(1.0f + __expf(-v));
}
// round-half-up fp32 -> bf16 bits (0.5 ulp max)
__device__ __forceinline__ unsigned short bfb(float a) {
    return (unsigned short)((__float_as_uint(a) + 0x8000u) >> 16);
}
// pack two f32 -> bf16x2 via v_perm (low = a, high = b)
__device__ __forceinline__ unsigned pk2(float a, float b) {
    return __builtin_amdgcn_perm(__float_as_uint(b) + 0x8000u,
                                 __float_as_uint(a) + 0x8000u, 0x07060302u);
}
__device__ __forceinline__ float b2f(unsigned short s) {
    return __uint_as_float((unsigned)s << 16);
}
// packed bf16x2 atomic add
__device__ __forceinline__ void atomic_pk_bf16(unsigned short* addr, unsigned pk) {
    asm volatile("global_atomic_pk_add_bf16 %0, %1, off"
                 :: "v"((unsigned long long)(size_t)addr), "v"(pk) : "memory");
}

// ---------------- fused setup: hist + weight-swizzle + embed + zero + xcopy --
// blocks [0,3125): deg histogram
// blocks [3125,3365): weight pre-swizzle (per layer 30720 shorts)
// blocks [3365,15865): embedding
// blocks [15865,17574): zero sum_f+tmsgb (7,000,000 B)
// blocks [17574,17721): copy x_in -> xo
__global__ __launch_bounds__(256) void setup_kernel(
    const int* __restrict__ row, int* __restrict__ deg,
    const float* __restrict__ eW1, const float* __restrict__ eW2,
    const float* __restrict__ cW1, const float* __restrict__ nW1,
    const float* __restrict__ nW2, unsigned short* __restrict__ wsW,
    const float* __restrict__ h_in, const float* __restrict__ emb_W,
    const float* __restrict__ emb_b, float* __restrict__ h_out,
    unsigned short* __restrict__ hb,
    char* __restrict__ zbase, const float* __restrict__ x_in,
    float* __restrict__ xo)
{
    const int b = blockIdx.x;
    if (b < 3125) {
        const int e = b * 256 + threadIdx.x;
        atomicAdd(&deg[row[e]], 1);
    } else if (b < 3365) {
        const int i = (b - 3125) * 256 + threadIdx.x;     // 0 .. 61439
        const int layer = i / 30720;
        const int rem = i - layer * 30720;
        float val;
        if (rem < 10240) {
            const int j = rem & 7, lane = (rem >> 3) & 63, nt = (rem >> 9) & 3, s = rem >> 11;
            const int kp = s * 32 + ((lane >> 4) << 3) + j;
            const int n  = nt * 16 + (lane & 15);
            if (kp > 136) val = 0.0f;
            else {
                const int k = (kp == 136) ? 0 : kp + 1;   // k'=136 is the r2 row
                val = eW1[layer * 137 * 64 + k * 64 + n];
            }
        } else if (rem < 14336) {
            const int r2 = rem - 10240;
            const int j = r2 & 7, lane = (r2 >> 3) & 63, nt = (r2 >> 9) & 3, s = r2 >> 11;
            val = eW2[layer * 4096 + (s * 32 + ((lane >> 4) << 3) + j) * 64 + nt * 16 + (lane & 15)];
        } else if (rem < 18432) {
            const int r3 = rem - 14336;
            const int j = r3 & 7, lane = (r3 >> 3) & 63, nt = (r3 >> 9) & 3, s = r3 >> 11;
            val = cW1[layer * 4096 + (s * 32 + ((lane >> 4) << 3) + j) * 64 + nt * 16 + (lane & 15)];
        } else if (rem < 26624) {
            const int r4 = rem - 18432;
            const int j = r4 & 7, lane = (r4 >> 3) & 63, nt = (r4 >> 9) & 3, s = r4 >> 11;
            const int kp = s * 32 + ((lane >> 4) << 3) + j;      // < 128
            val = nW1[layer * 8192 + kp * 64 + nt * 16 + (lane & 15)];
        } else {
            const int r5 = rem - 26624;
            const int j = r5 & 7, lane = (r5 >> 3) & 63, nt = (r5 >> 9) & 3, s = r5 >> 11;
            val = nW2[layer * 4096 + (s * 32 + ((lane >> 4) << 3) + j) * 64 + nt * 16 + (lane & 15)];
        }
        wsW[i] = bfb(val);
    } else if (b < 15865) {
        const int idx = (b - 3365) * 256 + threadIdx.x;   // over N*64
        const int n = idx >> 6, j = idx & 63;
        float acc = emb_b[j];
        #pragma unroll
        for (int k = 0; k < 16; ++k)
            acc += h_in[n * 16 + k] * emb_W[k * HH + j];
        h_out[idx] = acc;
        hb[idx] = bfb(acc);
    } else if (b < 17574) {
        const int t = (b - 15865) * 256 + threadIdx.x;
        if (t < 437500) {                                  // 7,000,000 / 16
            const uint4 z = {0u, 0u, 0u, 0u};
            *(uint4*)(zbase + (size_t)t * 16) = z;
        }
    } else {
        const int t = (b - 17574) * 256 + threadIdx.x;
        if (t < 37500)                                     // N*3 floats / 4
            ((uint4*)xo)[t] = ((const uint4*)x_in)[t];
    }
}

// parallel scan over NN, phase A: 200 blocks x 250-node chunks -> blocksum
__global__ __launch_bounds__(256) void scanA_kernel(const int* __restrict__ deg,
                                                    int* __restrict__ bsum) {
    __shared__ int ps[256];
    const int t = threadIdx.x;
    const int base = blockIdx.x * 250;
    int v = (t < 250) ? deg[base + t] : 0;
    ps[t] = v;
    __syncthreads();
    for (int off = 1; off < 256; off <<= 1) {
        const int u = (t >= off) ? ps[t - off] : 0;
        __syncthreads();
        ps[t] += u;
        __syncthreads();
    }
    if (t == 255) bsum[blockIdx.x] = ps[255];
}

// phase B: exclusive scan of 200 blocksums (single small block)
__global__ __launch_bounds__(256) void scanB_kernel(const int* __restrict__ bsum,
                                                    int* __restrict__ boff) {
    __shared__ int ps[256];
    const int t = threadIdx.x;
    int v = (t < 200) ? bsum[t] : 0;
    ps[t] = v;
    __syncthreads();
    for (int off = 1; off < 256; off <<= 1) {
        const int u = (t >= off) ? ps[t - off] : 0;
        __syncthreads();
        ps[t] += u;
        __syncthreads();
    }
    if (t < 200) boff[t] = ps[t] - v;     // exclusive
}

// phase C: per-chunk exclusive scan + global offset -> cur
__global__ __launch_bounds__(256) void scanC_kernel(const int* __restrict__ deg,
                                                    const int* __restrict__ boff,
                                                    int* __restrict__ cur) {
    __shared__ int ps[256];
    const int t = threadIdx.x;
    const int base = blockIdx.x * 250;
    int v = (t < 250) ? deg[base + t] : 0;
    ps[t] = v;
    __syncthreads();
    for (int off = 1; off < 256; off <<= 1) {
        const int u = (t >= off) ? ps[t - off] : 0;
        __syncthreads();
        ps[t] += u;
        __syncthreads();
    }
    if (t < 250)
        cur[base + t] = boff[blockIdx.x] + ps[t] - v;   // exclusive prefix
}

// one-pass counting-sort fill: materialize row/col/edge_fea in row-sorted order
__global__ __launch_bounds__(256) void fill_kernel(
    const int* __restrict__ row, const int* __restrict__ col,
    const float* __restrict__ efea, int* __restrict__ cur,
    int* __restrict__ rs, int* __restrict__ cs, unsigned short* __restrict__ efs)
{
    const int e = blockIdx.x * 256 + threadIdx.x;
    const int r = row[e];
    const int pos = atomicAdd(&cur[r], 1);
    rs[pos] = r;
    cs[pos] = col[e];
    const float4* ef = (const float4*)(efea + (size_t)e * 8);
    const float4 e0 = ef[0], e1 = ef[1];
    uint4 ue = { pk2(e0.x, e0.y), pk2(e0.z, e0.w), pk2(e1.x, e1.y), pk2(e1.z, e1.w) };
    *(uint4*)(efs + (size_t)pos * 8) = ue;
}

// ---------------- MFMA edge kernel: 16 sorted edges per wave ----------------
// Segmented flush with packed-bf16 atomics; rows sorted -> ~2 segments/tile.
__global__ __launch_bounds__(256, 7) void edge_mfma_kernel(
    const float* __restrict__ x, const unsigned short* __restrict__ hb,
    const int* __restrict__ rs, const int* __restrict__ cs,
    const unsigned short* __restrict__ efs,
    const unsigned short* __restrict__ w1b, const unsigned short* __restrict__ w2b,
    const unsigned short* __restrict__ cw1b,
    const float* __restrict__ b1, const float* __restrict__ b2,
    const float* __restrict__ cb1, const float* __restrict__ cw2,
    const float* __restrict__ cb2,
    float* __restrict__ sum_f, unsigned short* __restrict__ tmsgb)
{
    __shared__ __align__(16) unsigned short S[4][16][168];
    __shared__ float RV[4][16][4];
    __shared__ int   RI[4][16];

    const int tid = threadIdx.x;
    const int w = tid >> 6, lane = tid & 63;
    const int l15 = lane & 15, quad = lane >> 4;
    const int le = lane >> 2, sub = lane & 3;

    float b1v[4], b2v[4], cb1v[4], cw2v[4];
    #pragma unroll
    for (int nt = 0; nt < 4; ++nt) {
        b1v[nt]  = b1[nt * 16 + l15];
        b2v[nt]  = b2[nt * 16 + l15];
        cb1v[nt] = cb1[nt * 16 + l15];
        cw2v[nt] = cw2[nt * 16 + l15];
    }
    const float cb2s = cb2[0];

    {   // zero the K-pad [138,160) once; never overwritten afterwards
        unsigned short* Sr = &S[w][le][0];
        if (sub == 0) {
            *(unsigned*)&Sr[138] = 0u; *(unsigned*)&Sr[140] = 0u; *(unsigned*)&Sr[142] = 0u;
        } else if (sub == 1) {
            *(unsigned*)&Sr[144] = 0u; *(unsigned*)&Sr[146] = 0u;
            *(unsigned*)&Sr[148] = 0u; *(unsigned*)&Sr[150] = 0u;
        } else if (sub == 2) {
            *(unsigned*)&Sr[152] = 0u; *(unsigned*)&Sr[154] = 0u;
            *(unsigned*)&Sr[156] = 0u; *(unsigned*)&Sr[158] = 0u;
        }
    }
    WFENCE();

    for (int bt = blockIdx.x; bt < NTILE; bt += NB_EDGE) {
        const int t = bt * 4 + w;
        const int p = t * 16 + le;           // sorted edge position
        const int r = rs[p], c = cs[p];

        // ---- gather: 4 lanes per edge, bf16 uint4 copies ----
        unsigned short* Srow = &S[w][le][0];
        {
            const unsigned short* hr = hb + (size_t)r * HH + sub * 16;
            uint4 u0 = *(const uint4*)(hr);
            uint4 u1 = *(const uint4*)(hr + 8);
            *(uint4*)&Srow[sub * 16]     = u0;
            *(uint4*)&Srow[sub * 16 + 8] = u1;
            const unsigned short* hc = hb + (size_t)c * HH + sub * 16;
            uint4 v0 = *(const uint4*)(hc);
            uint4 v1 = *(const uint4*)(hc + 8);
            *(uint4*)&Srow[64 + sub * 16]     = v0;
            *(uint4*)&Srow[64 + sub * 16 + 8] = v1;
        }
        if (sub == 0) {
            const float rx = x[3 * r + 0] - x[3 * c + 0];
            const float ry = x[3 * r + 1] - x[3 * c + 1];
            const float rz = x[3 * r + 2] - x[3 * c + 2];
            const float r2 = rx * rx + ry * ry + rz * rz;
            RV[w][le][0] = rx; RV[w][le][1] = ry; RV[w][le][2] = rz;
            RI[w][le] = r;
            *(unsigned*)&Srow[136] = (unsigned)bfb(r2);   // zeroes col 137 too
        } else if (sub == 1) {
            *(uint4*)&Srow[128] = *(const uint4*)(efs + (size_t)p * 8);
        }
        WFENCE();

        // ---- GEMM1: S[16x160] @ W1[160x64] -> H1 (alias cols 0..63) ----
        bf16x8 af[5];
        #pragma unroll
        for (int s = 0; s < 5; ++s)
            af[s] = *(const bf16x8*)&S[w][l15][s * 32 + quad * 8];
        WFENCE();   // af in regs before H1 overwrites the same cols
        #pragma unroll
        for (int nt = 0; nt < 4; ++nt) {
            f32x4 a = {0.f, 0.f, 0.f, 0.f};
            #pragma unroll
            for (int s = 0; s < 5; ++s) {
                bf16x8 bf = *(const bf16x8*)(w1b + ((s * 4 + nt) * 64 + lane) * 8);
                a = __builtin_amdgcn_mfma_f32_16x16x32_bf16(af[s], bf, a, 0, 0, 0);
            }
            #pragma unroll
            for (int rr = 0; rr < 4; ++rr)
                S[w][quad * 4 + rr][nt * 16 + l15] = bfb(silu_f(a[rr] + b1v[nt]));
        }
        WFENCE();

        // ---- GEMM2: H1 @ W2 -> msg (alias back into cols 0..63) ----
        bf16x8 a2[2];
        #pragma unroll
        for (int s = 0; s < 2; ++s)
            a2[s] = *(const bf16x8*)&S[w][l15][s * 32 + quad * 8];
        WFENCE();   // a2 in regs before MS overwrites
        #pragma unroll
        for (int nt = 0; nt < 4; ++nt) {
            f32x4 m = {0.f, 0.f, 0.f, 0.f};
            #pragma unroll
            for (int s = 0; s < 2; ++s) {
                bf16x8 bf = *(const bf16x8*)(w2b + ((s * 4 + nt) * 64 + lane) * 8);
                m = __builtin_amdgcn_mfma_f32_16x16x32_bf16(a2[s], bf, m, 0, 0, 0);
            }
            #pragma unroll
            for (int rr = 0; rr < 4; ++rr)
                S[w][quad * 4 + rr][nt * 16 + l15] = bfb(silu_f(m[rr] + b2v[nt]));
        }
        WFENCE();

        // ---- GEMM3: msg @ cW1 -> c1; dot cW2 -> cm (cols 160..162) ----
        bf16x8 a3[2];
        #pragma unroll
        for (int s = 0; s < 2; ++s)
            a3[s] = *(const bf16x8*)&S[w][l15][s * 32 + quad * 8];
        float pr[4] = {0.f, 0.f, 0.f, 0.f};
        #pragma unroll
        for (int nt = 0; nt < 4; ++nt) {
            f32x4 q = {0.f, 0.f, 0.f, 0.f};
            #pragma unroll
            for (int s = 0; s < 2; ++s) {
                bf16x8 bf = *(const bf16x8*)(cw1b + ((s * 4 + nt) * 64 + lane) * 8);
                q = __builtin_amdgcn_mfma_f32_16x16x32_bf16(a3[s], bf, q, 0, 0, 0);
            }
            #pragma unroll
            for (int rr = 0; rr < 4; ++rr)
                pr[rr] += silu_f(q[rr] + cb1v[nt]) * cw2v[nt];
        }
        #pragma unroll
        for (int rr = 0; rr < 4; ++rr) {
            float tt = pr[rr];
            tt += __shfl_xor(tt, 1, 64);
            tt += __shfl_xor(tt, 2, 64);
            tt += __shfl_xor(tt, 4, 64);
            tt += __shfl_xor(tt, 8, 64);
            if (l15 == 0) *(float*)&S[w][quad * 4 + rr][160] = tt + cb2s;
        }
        WFENCE();

        // ---- segmented flush: rows sorted by RI within the tile ----
        if (lane < 32) {   // msg -> tmsgb: lane owns cols {2l, 2l+1}, pk atomic
            unsigned both = *(const unsigned*)&S[w][0][2 * lane];
            float ax = b2f((unsigned short)(both & 0xffffu));
            float ay = b2f((unsigned short)(both >> 16));
            int cur_r = RI[w][0];
            #pragma unroll
            for (int g = 1; g < 16; ++g) {
                const int ri = RI[w][g];
                unsigned bv = *(const unsigned*)&S[w][g][2 * lane];
                const float vx = b2f((unsigned short)(bv & 0xffffu));
                const float vy = b2f((unsigned short)(bv >> 16));
                if (ri != cur_r) {
                    atomic_pk_bf16(&tmsgb[(size_t)cur_r * HH + 2 * lane], pk2(ax, ay));
                    ax = 0.f; ay = 0.f; cur_r = ri;
                }
                ax += vx; ay += vy;
            }
            atomic_pk_bf16(&tmsgb[(size_t)cur_r * HH + 2 * lane], pk2(ax, ay));
        } else if ((lane & 31) < 3) {   // f = rij*cm -> sum_f (fp32, tiny)
            const int sl = lane & 31;
            float acc = RV[w][0][sl] * (*(const float*)&S[w][0][160]);
            int cur_r = RI[w][0];
            #pragma unroll
            for (int g = 1; g < 16; ++g) {
                const int ri = RI[w][g];
                const float v = RV[w][g][sl] * (*(const float*)&S[w][g][160]);
                if (ri != cur_r) {
                    atomicAdd(&sum_f[3 * cur_r + sl], acc);
                    acc = 0.f; cur_r = ri;
                }
                acc += v;
            }
            atomicAdd(&sum_f[3 * cur_r + sl], acc);
        }
        WFENCE();
    }
}

// ---------------- MFMA node kernel: 16 nodes per wave ----------------
// Reads bf16 tmsgb directly; zeroes tmsgb/sum_f after use (next layer's init).
__global__ __launch_bounds__(256) void node_mfma_kernel(
    float* __restrict__ x, float* __restrict__ h,
    unsigned short* __restrict__ hb,
    float* __restrict__ sum_f, const int* __restrict__ deg,
    unsigned short* __restrict__ tmsgb,
    const unsigned short* __restrict__ nw1b, const unsigned short* __restrict__ nw2b,
    const float* __restrict__ nb1, const float* __restrict__ nb2)
{
    __shared__ __align__(16) unsigned short S[4][16][136];
    const int tid = threadIdx.x;
    const int w = tid >> 6, lane = tid & 63;
    const int l15 = lane & 15, quad = lane >> 4;
    const int le = lane >> 2, sub = lane & 3;
    const int t = blockIdx.x * 4 + w;
    if (t >= NN / 16) return;                      // 3125 waves exactly

    // gather (fully coalesced): [hb | tmsgb] -> S[16][128]; zero tmsgb after
    {
        unsigned short* Srow = &S[w][le][0];
        const int n = t * 16 + le;
        const unsigned short* hr = hb + (size_t)n * HH + sub * 16;
        *(uint4*)&Srow[sub * 16]     = *(const uint4*)(hr);
        *(uint4*)&Srow[sub * 16 + 8] = *(const uint4*)(hr + 8);
        unsigned short* tm = tmsgb + (size_t)n * HH + sub * 16;
        *(uint4*)&Srow[64 + sub * 16]     = *(const uint4*)(tm);
        *(uint4*)&Srow[64 + sub * 16 + 8] = *(const uint4*)(tm + 8);
        const uint4 z = {0u, 0u, 0u, 0u};
        *(uint4*)(tm)     = z;
        *(uint4*)(tm + 8) = z;
    }
    // x update: one lane per node; zero sum_f after
    if (lane < 16) {
        const int nn = t * 16 + lane;
        const float cn = fmaxf((float)deg[nn], 1.0f);
        const float rc = __builtin_amdgcn_rcpf(cn);
        #pragma unroll
        for (int d3 = 0; d3 < 3; ++d3) {
            float tf = sum_f[3 * nn + d3] * rc;
            tf = fminf(fmaxf(tf, -100.0f), 100.0f);
            x[3 * nn + d3] += tf;
            sum_f[3 * nn + d3] = 0.0f;
        }
    }
    WFENCE();

    // GEMM1: [16x128] @ nW1[128x64] -> SiLU -> alias cols 0..63
    bf16x8 af[4];
    #pragma unroll
    for (int s = 0; s < 4; ++s)
        af[s] = *(const bf16x8*)&S[w][l15][s * 32 + quad * 8];
    WFENCE();
    float nb1v[4], nb2v[4];
    #pragma unroll
    for (int nt = 0; nt < 4; ++nt) {
        nb1v[nt] = nb1[nt * 16 + l15];
        nb2v[nt] = nb2[nt * 16 + l15];
    }
    #pragma unroll
    for (int nt = 0; nt < 4; ++nt) {
        f32x4 a = {0.f, 0.f, 0.f, 0.f};
        #pragma unroll
        for (int s = 0; s < 4; ++s) {
            bf16x8 bf = *(const bf16x8*)(nw1b + ((s * 4 + nt) * 64 + lane) * 8);
            a = __builtin_amdgcn_mfma_f32_16x16x32_bf16(af[s], bf, a, 0, 0, 0);
        }
        #pragma unroll
        for (int rr = 0; rr < 4; ++rr)
            S[w][quad * 4 + rr][nt * 16 + l15] = bfb(silu_f(a[rr] + nb1v[nt]));
    }
    WFENCE();

    // GEMM2: [16x64] @ nW2[64x64] -> h (no act)
    bf16x8 a2[2];
    #pragma unroll
    for (int s = 0; s < 2; ++s)
        a2[s] = *(const bf16x8*)&S[w][l15][s * 32 + quad * 8];
    #pragma unroll
    for (int nt = 0; nt < 4; ++nt) {
        f32x4 m = {0.f, 0.f, 0.f, 0.f};
        #pragma unroll
        for (int s = 0; s < 2; ++s) {
            bf16x8 bf = *(const bf16x8*)(nw2b + ((s * 4 + nt) * 64 + lane) * 8);
            m = __builtin_amdgcn_mfma_f32_16x16x32_bf16(a2[s], bf, m, 0, 0, 0);
        }
        #pragma unroll
        for (int rr = 0; rr < 4; ++rr) {
            const float v = m[rr] + nb2v[nt];
            const size_t nd = (size_t)(t * 16 + quad * 4 + rr) * HH + nt * 16 + l15;
            h[nd] = v;
            hb[nd] = bfb(v);
        }
    }
}

extern "C" void kernel_launch(void* const* d_in, const int* in_sizes, int n_in,
                              void* d_out, int out_size, void* d_ws, size_t ws_size,
                              hipStream_t stream) {
    const float* x_in  = (const float*)d_in[0];
    const float* h_in  = (const float*)d_in[1];
    const int*   row   = (const int*)d_in[2];
    const int*   col   = (const int*)d_in[3];
    const float* efea  = (const float*)d_in[4];
    const float* emb_W = (const float*)d_in[5];
    const float* emb_b = (const float*)d_in[6];
    const float* eW1   = (const float*)d_in[7];
    const float* eb1   = (const float*)d_in[8];
    const float* eW2   = (const float*)d_in[9];
    const float* eb2   = (const float*)d_in[10];
    const float* cW1   = (const float*)d_in[11];
    const float* cb1   = (const float*)d_in[12];
    const float* cW2   = (const float*)d_in[13];
    const float* cb2   = (const float*)d_in[14];
    const float* nW1   = (const float*)d_in[15];
    const float* nb1   = (const float*)d_in[16];
    const float* nW2   = (const float*)d_in[17];
    const float* nb2   = (const float*)d_in[18];

    float* out = (float*)d_out;
    float* xo = out;                 // N*3
    float* ho = out + NN * 3;        // N*64

    // workspace layout (16B-aligned segments)
    char* wsb = (char*)d_ws;
    float* sum_f = (float*)wsb;                                  //    600,000 B
    unsigned short* tmsgb = (unsigned short*)(wsb + 600000);     //  6,400,000 B
    unsigned short* efs = (unsigned short*)(wsb + 7000000);      // 12,800,000 B
    unsigned short* hb  = (unsigned short*)(wsb + 19800000);     //  6,400,000 B
    unsigned short* wsW = (unsigned short*)(wsb + 26200000);     //    122,880 B
    int* deg    = (int*)(wsb + 26322880);                        //    200,000 B
    int* cur    = (int*)(wsb + 26522880);                        //    200,000 B
    int* rs     = (int*)(wsb + 26722880);                        //  3,200,000 B
    int* cs     = (int*)(wsb + 29922880);                        //  3,200,000 B
    int* bsum   = (int*)(wsb + 33122880);                        //        800 B
    int* boff   = (int*)(wsb + 33123680);                        //        800 B

    // zero deg, then fused setup (hist + swizzle + embed + zero + x copy)
    hipMemsetAsync(deg, 0, 200000, stream);
    setup_kernel<<<17721, 256, 0, stream>>>(
        row, deg,
        eW1, eW2, cW1, nW1, nW2, wsW,
        h_in, emb_W, emb_b, ho, hb,
        wsb, x_in, xo);
    // row scan + counting sort
    scanA_kernel<<<200, 256, 0, stream>>>(deg, bsum);
    scanB_kernel<<<1, 256, 0, stream>>>(bsum, boff);
    scanC_kernel<<<200, 256, 0, stream>>>(deg, boff, cur);
    fill_kernel<<<MM / 256, 256, 0, stream>>>(row, col, efea, cur, rs, cs, efs);

    for (int i = 0; i < 2; ++i) {
        const unsigned short* L = wsW + i * 30720;
        edge_mfma_kernel<<<NB_EDGE, 256, 0, stream>>>(
            xo, hb, rs, cs, efs,
            L, L + 10240, L + 14336,
            eb1 + i * 64, eb2 + i * 64, cb1 + i * 64, cW2 + i * 64, cb2 + i,
            sum_f, tmsgb);
        node_mfma_kernel<<<(NN / 16 + 3) / 4, 256, 0, stream>>>(
            xo, ho, hb, sum_f, deg, tmsgb,
            L + 18432, L + 26624, nb1 + i * 64, nb2 + i * 64);
    }
}

// Round 15
// 596.616 us; speedup vs baseline: 1.0795x; 1.0097x over previous
//
#include <hip/hip_runtime.h>
#include <math.h>

#define NN 50000
#define MM 800000
#define HH 64
#define NB_EDGE 1792
#define NTILE 12500                 // MM / 64 edges per block-tile

typedef short bf16x8 __attribute__((ext_vector_type(8)));
typedef float f32x4  __attribute__((ext_vector_type(4)));

// per-wave LDS fence: all LDS regions are wave-private; lockstep + lgkmcnt
// drain replaces __syncthreads
#define WFENCE() asm volatile("s_waitcnt lgkmcnt(0)" ::: "memory")

__device__ __forceinline__ float silu_f(float v) {
    return v * __builtin_amdgcn_rcpf(1.0f + __expf(-v));
}
// round-half-up fp32 -> bf16 bits (0.5 ulp max)
__device__ __forceinline__ unsigned short bfb(float a) {
    return (unsigned short)((__float_as_uint(a) + 0x8000u) >> 16);
}
// pack two f32 -> bf16x2 via v_perm (low = a, high = b)
__device__ __forceinline__ unsigned pk2(float a, float b) {
    return __builtin_amdgcn_perm(__float_as_uint(b) + 0x8000u,
                                 __float_as_uint(a) + 0x8000u, 0x07060302u);
}
__device__ __forceinline__ float b2f(unsigned short s) {
    return __uint_as_float((unsigned)s << 16);
}
// packed bf16x2 atomic add
__device__ __forceinline__ void atomic_pk_bf16(unsigned short* addr, unsigned pk) {
    asm volatile("global_atomic_pk_add_bf16 %0, %1, off"
                 :: "v"((unsigned long long)(size_t)addr), "v"(pk) : "memory");
}

// ---------------- fused setup ----------------
// blocks [0,3125): deg histogram
// blocks [3125,3365): weight pre-swizzle (per layer 30720 shorts)
// blocks [3365,15865): embedding
// blocks [15865,17574): zero sum_f+tmsgb (7,000,000 B)
// blocks [17574,17721): copy x_in -> xo (uint4)
// blocks [17721,17917): build padded x4 mirror
__global__ __launch_bounds__(256) void setup_kernel(
    const int* __restrict__ row, int* __restrict__ deg,
    const float* __restrict__ eW1, const float* __restrict__ eW2,
    const float* __restrict__ cW1, const float* __restrict__ nW1,
    const float* __restrict__ nW2, unsigned short* __restrict__ wsW,
    const float* __restrict__ h_in, const float* __restrict__ emb_W,
    const float* __restrict__ emb_b, float* __restrict__ h_out,
    unsigned short* __restrict__ hb,
    char* __restrict__ zbase, const float* __restrict__ x_in,
    float* __restrict__ xo, float* __restrict__ x4)
{
    const int b = blockIdx.x;
    if (b < 3125) {
        const int e = b * 256 + threadIdx.x;
        atomicAdd(&deg[row[e]], 1);
    } else if (b < 3365) {
        const int i = (b - 3125) * 256 + threadIdx.x;     // 0 .. 61439
        const int layer = i / 30720;
        const int rem = i - layer * 30720;
        float val;
        if (rem < 10240) {
            const int j = rem & 7, lane = (rem >> 3) & 63, nt = (rem >> 9) & 3, s = rem >> 11;
            const int kp = s * 32 + ((lane >> 4) << 3) + j;
            const int n  = nt * 16 + (lane & 15);
            if (kp > 136) val = 0.0f;
            else {
                const int k = (kp == 136) ? 0 : kp + 1;   // k'=136 is the r2 row
                val = eW1[layer * 137 * 64 + k * 64 + n];
            }
        } else if (rem < 14336) {
            const int r2 = rem - 10240;
            const int j = r2 & 7, lane = (r2 >> 3) & 63, nt = (r2 >> 9) & 3, s = r2 >> 11;
            val = eW2[layer * 4096 + (s * 32 + ((lane >> 4) << 3) + j) * 64 + nt * 16 + (lane & 15)];
        } else if (rem < 18432) {
            const int r3 = rem - 14336;
            const int j = r3 & 7, lane = (r3 >> 3) & 63, nt = (r3 >> 9) & 3, s = r3 >> 11;
            val = cW1[layer * 4096 + (s * 32 + ((lane >> 4) << 3) + j) * 64 + nt * 16 + (lane & 15)];
        } else if (rem < 26624) {
            const int r4 = rem - 18432;
            const int j = r4 & 7, lane = (r4 >> 3) & 63, nt = (r4 >> 9) & 3, s = r4 >> 11;
            const int kp = s * 32 + ((lane >> 4) << 3) + j;      // < 128
            val = nW1[layer * 8192 + kp * 64 + nt * 16 + (lane & 15)];
        } else {
            const int r5 = rem - 26624;
            const int j = r5 & 7, lane = (r5 >> 3) & 63, nt = (r5 >> 9) & 3, s = r5 >> 11;
            val = nW2[layer * 4096 + (s * 32 + ((lane >> 4) << 3) + j) * 64 + nt * 16 + (lane & 15)];
        }
        wsW[i] = bfb(val);
    } else if (b < 15865) {
        const int idx = (b - 3365) * 256 + threadIdx.x;   // over N*64
        const int n = idx >> 6, j = idx & 63;
        float acc = emb_b[j];
        #pragma unroll
        for (int k = 0; k < 16; ++k)
            acc += h_in[n * 16 + k] * emb_W[k * HH + j];
        h_out[idx] = acc;
        hb[idx] = bfb(acc);
    } else if (b < 17574) {
        const int t = (b - 15865) * 256 + threadIdx.x;
        if (t < 437500) {                                  // 7,000,000 / 16
            const uint4 z = {0u, 0u, 0u, 0u};
            *(uint4*)(zbase + (size_t)t * 16) = z;
        }
    } else if (b < 17721) {
        const int t = (b - 17574) * 256 + threadIdx.x;
        if (t < 37500)                                     // N*3 floats / 4
            ((uint4*)xo)[t] = ((const uint4*)x_in)[t];
    } else {
        const int n = (b - 17721) * 256 + threadIdx.x;
        if (n < NN) {
            float4 v;
            v.x = x_in[3 * n + 0];
            v.y = x_in[3 * n + 1];
            v.z = x_in[3 * n + 2];
            v.w = 0.0f;
            ((float4*)x4)[n] = v;
        }
    }
}

// parallel scan over NN, phase A: 200 blocks x 250-node chunks -> blocksum
__global__ __launch_bounds__(256) void scanA_kernel(const int* __restrict__ deg,
                                                    int* __restrict__ bsum) {
    __shared__ int ps[256];
    const int t = threadIdx.x;
    const int base = blockIdx.x * 250;
    int v = (t < 250) ? deg[base + t] : 0;
    ps[t] = v;
    __syncthreads();
    for (int off = 1; off < 256; off <<= 1) {
        const int u = (t >= off) ? ps[t - off] : 0;
        __syncthreads();
        ps[t] += u;
        __syncthreads();
    }
    if (t == 255) bsum[blockIdx.x] = ps[255];
}

// phase B: exclusive scan of 200 blocksums (single small block)
__global__ __launch_bounds__(256) void scanB_kernel(const int* __restrict__ bsum,
                                                    int* __restrict__ boff) {
    __shared__ int ps[256];
    const int t = threadIdx.x;
    int v = (t < 200) ? bsum[t] : 0;
    ps[t] = v;
    __syncthreads();
    for (int off = 1; off < 256; off <<= 1) {
        const int u = (t >= off) ? ps[t - off] : 0;
        __syncthreads();
        ps[t] += u;
        __syncthreads();
    }
    if (t < 200) boff[t] = ps[t] - v;     // exclusive
}

// phase C: per-chunk exclusive scan + global offset -> cur
__global__ __launch_bounds__(256) void scanC_kernel(const int* __restrict__ deg,
                                                    const int* __restrict__ boff,
                                                    int* __restrict__ cur) {
    __shared__ int ps[256];
    const int t = threadIdx.x;
    const int base = blockIdx.x * 250;
    int v = (t < 250) ? deg[base + t] : 0;
    ps[t] = v;
    __syncthreads();
    for (int off = 1; off < 256; off <<= 1) {
        const int u = (t >= off) ? ps[t - off] : 0;
        __syncthreads();
        ps[t] += u;
        __syncthreads();
    }
    if (t < 250)
        cur[base + t] = boff[blockIdx.x] + ps[t] - v;   // exclusive prefix
}

// one-pass counting-sort fill: rc (int2 interleaved) + efs in row-sorted order
__global__ __launch_bounds__(256) void fill_kernel(
    const int* __restrict__ row, const int* __restrict__ col,
    const float* __restrict__ efea, int* __restrict__ cur,
    int2* __restrict__ rc, unsigned short* __restrict__ efs)
{
    const int e = blockIdx.x * 256 + threadIdx.x;
    const int r = row[e];
    const int pos = atomicAdd(&cur[r], 1);
    int2 v; v.x = r; v.y = col[e];
    rc[pos] = v;                                       // one 8B scatter
    const float4* ef = (const float4*)(efea + (size_t)e * 8);
    const float4 e0 = ef[0], e1 = ef[1];
    uint4 ue = { pk2(e0.x, e0.y), pk2(e0.z, e0.w), pk2(e1.x, e1.y), pk2(e1.z, e1.w) };
    *(uint4*)(efs + (size_t)pos * 8) = ue;
}

// ---------------- MFMA edge kernel: 16 sorted edges per wave ----------------
// Segmented flush with packed-bf16 atomics; rows sorted -> ~2 segments/tile.
__global__ __launch_bounds__(256, 7) void edge_mfma_kernel(
    const float* __restrict__ x4, const unsigned short* __restrict__ hb,
    const int2* __restrict__ rc, const unsigned short* __restrict__ efs,
    const unsigned short* __restrict__ w1b, const unsigned short* __restrict__ w2b,
    const unsigned short* __restrict__ cw1b,
    const float* __restrict__ b1, const float* __restrict__ b2,
    const float* __restrict__ cb1, const float* __restrict__ cw2,
    const float* __restrict__ cb2,
    float* __restrict__ sum_f, unsigned short* __restrict__ tmsgb)
{
    __shared__ __align__(16) unsigned short S[4][16][168];
    __shared__ float RV[4][16][4];
    __shared__ int   RI[4][16];

    const int tid = threadIdx.x;
    const int w = tid >> 6, lane = tid & 63;
    const int l15 = lane & 15, quad = lane >> 4;
    const int le = lane >> 2, sub = lane & 3;

    float b1v[4], b2v[4], cb1v[4], cw2v[4];
    #pragma unroll
    for (int nt = 0; nt < 4; ++nt) {
        b1v[nt]  = b1[nt * 16 + l15];
        b2v[nt]  = b2[nt * 16 + l15];
        cb1v[nt] = cb1[nt * 16 + l15];
        cw2v[nt] = cw2[nt * 16 + l15];
    }
    const float cb2s = cb2[0];

    {   // zero the K-pad [138,160) once; never overwritten afterwards
        unsigned short* Sr = &S[w][le][0];
        if (sub == 0) {
            *(unsigned*)&Sr[138] = 0u; *(unsigned*)&Sr[140] = 0u; *(unsigned*)&Sr[142] = 0u;
        } else if (sub == 1) {
            *(unsigned*)&Sr[144] = 0u; *(unsigned*)&Sr[146] = 0u;
            *(unsigned*)&Sr[148] = 0u; *(unsigned*)&Sr[150] = 0u;
        } else if (sub == 2) {
            *(unsigned*)&Sr[152] = 0u; *(unsigned*)&Sr[154] = 0u;
            *(unsigned*)&Sr[156] = 0u; *(unsigned*)&Sr[158] = 0u;
        }
    }
    WFENCE();

    for (int bt = blockIdx.x; bt < NTILE; bt += NB_EDGE) {
        const int t = bt * 4 + w;
        const int p = t * 16 + le;           // sorted edge position
        const int2 rcv = rc[p];
        const int r = rcv.x, c = rcv.y;

        // ---- gather: 4 lanes per edge, bf16 uint4 copies ----
        unsigned short* Srow = &S[w][le][0];
        {
            const unsigned short* hr = hb + (size_t)r * HH + sub * 16;
            uint4 u0 = *(const uint4*)(hr);
            uint4 u1 = *(const uint4*)(hr + 8);
            *(uint4*)&Srow[sub * 16]     = u0;
            *(uint4*)&Srow[sub * 16 + 8] = u1;
            const unsigned short* hc = hb + (size_t)c * HH + sub * 16;
            uint4 v0 = *(const uint4*)(hc);
            uint4 v1 = *(const uint4*)(hc + 8);
            *(uint4*)&Srow[64 + sub * 16]     = v0;
            *(uint4*)&Srow[64 + sub * 16 + 8] = v1;
        }
        if (sub == 0) {
            const float4 xr = ((const float4*)x4)[r];
            const float4 xc = ((const float4*)x4)[c];
            const float rx = xr.x - xc.x;
            const float ry = xr.y - xc.y;
            const float rz = xr.z - xc.z;
            const float r2 = rx * rx + ry * ry + rz * rz;
            RV[w][le][0] = rx; RV[w][le][1] = ry; RV[w][le][2] = rz;
            RI[w][le] = r;
            *(unsigned*)&Srow[136] = (unsigned)bfb(r2);   // zeroes col 137 too
        } else if (sub == 1) {
            *(uint4*)&Srow[128] = *(const uint4*)(efs + (size_t)p * 8);
        }
        WFENCE();

        // ---- GEMM1: S[16x160] @ W1[160x64] -> H1 (alias cols 0..63) ----
        bf16x8 af[5];
        #pragma unroll
        for (int s = 0; s < 5; ++s)
            af[s] = *(const bf16x8*)&S[w][l15][s * 32 + quad * 8];
        WFENCE();   // af in regs before H1 overwrites the same cols
        #pragma unroll
        for (int nt = 0; nt < 4; ++nt) {
            f32x4 a = {0.f, 0.f, 0.f, 0.f};
            #pragma unroll
            for (int s = 0; s < 5; ++s) {
                bf16x8 bf = *(const bf16x8*)(w1b + ((s * 4 + nt) * 64 + lane) * 8);
                a = __builtin_amdgcn_mfma_f32_16x16x32_bf16(af[s], bf, a, 0, 0, 0);
            }
            #pragma unroll
            for (int rr = 0; rr < 4; ++rr)
                S[w][quad * 4 + rr][nt * 16 + l15] = bfb(silu_f(a[rr] + b1v[nt]));
        }
        WFENCE();

        // ---- GEMM2: H1 @ W2 -> msg (alias back into cols 0..63) ----
        bf16x8 a2[2];
        #pragma unroll
        for (int s = 0; s < 2; ++s)
            a2[s] = *(const bf16x8*)&S[w][l15][s * 32 + quad * 8];
        WFENCE();   // a2 in regs before MS overwrites
        #pragma unroll
        for (int nt = 0; nt < 4; ++nt) {
            f32x4 m = {0.f, 0.f, 0.f, 0.f};
            #pragma unroll
            for (int s = 0; s < 2; ++s) {
                bf16x8 bf = *(const bf16x8*)(w2b + ((s * 4 + nt) * 64 + lane) * 8);
                m = __builtin_amdgcn_mfma_f32_16x16x32_bf16(a2[s], bf, m, 0, 0, 0);
            }
            #pragma unroll
            for (int rr = 0; rr < 4; ++rr)
                S[w][quad * 4 + rr][nt * 16 + l15] = bfb(silu_f(m[rr] + b2v[nt]));
        }
        WFENCE();

        // ---- GEMM3: msg @ cW1 -> c1; dot cW2 -> cm (cols 160..162) ----
        bf16x8 a3[2];
        #pragma unroll
        for (int s = 0; s < 2; ++s)
            a3[s] = *(const bf16x8*)&S[w][l15][s * 32 + quad * 8];
        float pr[4] = {0.f, 0.f, 0.f, 0.f};
        #pragma unroll
        for (int nt = 0; nt < 4; ++nt) {
            f32x4 q = {0.f, 0.f, 0.f, 0.f};
            #pragma unroll
            for (int s = 0; s < 2; ++s) {
                bf16x8 bf = *(const bf16x8*)(cw1b + ((s * 4 + nt) * 64 + lane) * 8);
                q = __builtin_amdgcn_mfma_f32_16x16x32_bf16(a3[s], bf, q, 0, 0, 0);
            }
            #pragma unroll
            for (int rr = 0; rr < 4; ++rr)
                pr[rr] += silu_f(q[rr] + cb1v[nt]) * cw2v[nt];
        }
        #pragma unroll
        for (int rr = 0; rr < 4; ++rr) {
            float tt = pr[rr];
            tt += __shfl_xor(tt, 1, 64);
            tt += __shfl_xor(tt, 2, 64);
            tt += __shfl_xor(tt, 4, 64);
            tt += __shfl_xor(tt, 8, 64);
            if (l15 == 0) *(float*)&S[w][quad * 4 + rr][160] = tt + cb2s;
        }
        WFENCE();

        // ---- segmented flush: rows sorted by RI within the tile ----
        if (lane < 32) {   // msg -> tmsgb: lane owns cols {2l, 2l+1}, pk atomic
            unsigned both = *(const unsigned*)&S[w][0][2 * lane];
            float ax = b2f((unsigned short)(both & 0xffffu));
            float ay = b2f((unsigned short)(both >> 16));
            int cur_r = RI[w][0];
            #pragma unroll
            for (int g = 1; g < 16; ++g) {
                const int ri = RI[w][g];
                unsigned bv = *(const unsigned*)&S[w][g][2 * lane];
                const float vx = b2f((unsigned short)(bv & 0xffffu));
                const float vy = b2f((unsigned short)(bv >> 16));
                if (ri != cur_r) {
                    atomic_pk_bf16(&tmsgb[(size_t)cur_r * HH + 2 * lane], pk2(ax, ay));
                    ax = 0.f; ay = 0.f; cur_r = ri;
                }
                ax += vx; ay += vy;
            }
            atomic_pk_bf16(&tmsgb[(size_t)cur_r * HH + 2 * lane], pk2(ax, ay));
        } else if ((lane & 31) < 3) {   // f = rij*cm -> sum_f (fp32, tiny)
            const int sl = lane & 31;
            float acc = RV[w][0][sl] * (*(const float*)&S[w][0][160]);
            int cur_r = RI[w][0];
            #pragma unroll
            for (int g = 1; g < 16; ++g) {
                const int ri = RI[w][g];
                const float v = RV[w][g][sl] * (*(const float*)&S[w][g][160]);
                if (ri != cur_r) {
                    atomicAdd(&sum_f[3 * cur_r + sl], acc);
                    acc = 0.f; cur_r = ri;
                }
                acc += v;
            }
            atomicAdd(&sum_f[3 * cur_r + sl], acc);
        }
        WFENCE();
    }
}

// ---------------- MFMA node kernel: 16 nodes per wave ----------------
// Reads bf16 tmsgb directly; zeroes tmsgb/sum_f after use (next layer's init).
// Updates both xo (output) and x4 (padded mirror for next layer's edge pass).
__global__ __launch_bounds__(256) void node_mfma_kernel(
    float* __restrict__ x, float* __restrict__ x4, float* __restrict__ h,
    unsigned short* __restrict__ hb,
    float* __restrict__ sum_f, const int* __restrict__ deg,
    unsigned short* __restrict__ tmsgb,
    const unsigned short* __restrict__ nw1b, const unsigned short* __restrict__ nw2b,
    const float* __restrict__ nb1, const float* __restrict__ nb2)
{
    __shared__ __align__(16) unsigned short S[4][16][136];
    const int tid = threadIdx.x;
    const int w = tid >> 6, lane = tid & 63;
    const int l15 = lane & 15, quad = lane >> 4;
    const int le = lane >> 2, sub = lane & 3;
    const int t = blockIdx.x * 4 + w;
    if (t >= NN / 16) return;                      // 3125 waves exactly

    // gather (fully coalesced): [hb | tmsgb] -> S[16][128]; zero tmsgb after
    {
        unsigned short* Srow = &S[w][le][0];
        const int n = t * 16 + le;
        const unsigned short* hr = hb + (size_t)n * HH + sub * 16;
        *(uint4*)&Srow[sub * 16]     = *(const uint4*)(hr);
        *(uint4*)&Srow[sub * 16 + 8] = *(const uint4*)(hr + 8);
        unsigned short* tm = tmsgb + (size_t)n * HH + sub * 16;
        *(uint4*)&Srow[64 + sub * 16]     = *(const uint4*)(tm);
        *(uint4*)&Srow[64 + sub * 16 + 8] = *(const uint4*)(tm + 8);
        const uint4 z = {0u, 0u, 0u, 0u};
        *(uint4*)(tm)     = z;
        *(uint4*)(tm + 8) = z;
    }
    // x update: one lane per node; zero sum_f after
    if (lane < 16) {
        const int nn = t * 16 + lane;
        const float cn = fmaxf((float)deg[nn], 1.0f);
        const float rc = __builtin_amdgcn_rcpf(cn);
        #pragma unroll
        for (int d3 = 0; d3 < 3; ++d3) {
            float tf = sum_f[3 * nn + d3] * rc;
            tf = fminf(fmaxf(tf, -100.0f), 100.0f);
            x[3 * nn + d3] += tf;
            x4[4 * nn + d3] += tf;
            sum_f[3 * nn + d3] = 0.0f;
        }
    }
    WFENCE();

    // GEMM1: [16x128] @ nW1[128x64] -> SiLU -> alias cols 0..63
    bf16x8 af[4];
    #pragma unroll
    for (int s = 0; s < 4; ++s)
        af[s] = *(const bf16x8*)&S[w][l15][s * 32 + quad * 8];
    WFENCE();
    float nb1v[4], nb2v[4];
    #pragma unroll
    for (int nt = 0; nt < 4; ++nt) {
        nb1v[nt] = nb1[nt * 16 + l15];
        nb2v[nt] = nb2[nt * 16 + l15];
    }
    #pragma unroll
    for (int nt = 0; nt < 4; ++nt) {
        f32x4 a = {0.f, 0.f, 0.f, 0.f};
        #pragma unroll
        for (int s = 0; s < 4; ++s) {
            bf16x8 bf = *(const bf16x8*)(nw1b + ((s * 4 + nt) * 64 + lane) * 8);
            a = __builtin_amdgcn_mfma_f32_16x16x32_bf16(af[s], bf, a, 0, 0, 0);
        }
        #pragma unroll
        for (int rr = 0; rr < 4; ++rr)
            S[w][quad * 4 + rr][nt * 16 + l15] = bfb(silu_f(a[rr] + nb1v[nt]));
    }
    WFENCE();

    // GEMM2: [16x64] @ nW2[64x64] -> h (no act)
    bf16x8 a2[2];
    #pragma unroll
    for (int s = 0; s < 2; ++s)
        a2[s] = *(const bf16x8*)&S[w][l15][s * 32 + quad * 8];
    #pragma unroll
    for (int nt = 0; nt < 4; ++nt) {
        f32x4 m = {0.f, 0.f, 0.f, 0.f};
        #pragma unroll
        for (int s = 0; s < 2; ++s) {
            bf16x8 bf = *(const bf16x8*)(nw2b + ((s * 4 + nt) * 64 + lane) * 8);
            m = __builtin_amdgcn_mfma_f32_16x16x32_bf16(a2[s], bf, m, 0, 0, 0);
        }
        #pragma unroll
        for (int rr = 0; rr < 4; ++rr) {
            const float v = m[rr] + nb2v[nt];
            const size_t nd = (size_t)(t * 16 + quad * 4 + rr) * HH + nt * 16 + l15;
            h[nd] = v;
            hb[nd] = bfb(v);
        }
    }
}

extern "C" void kernel_launch(void* const* d_in, const int* in_sizes, int n_in,
                              void* d_out, int out_size, void* d_ws, size_t ws_size,
                              hipStream_t stream) {
    const float* x_in  = (const float*)d_in[0];
    const float* h_in  = (const float*)d_in[1];
    const int*   row   = (const int*)d_in[2];
    const int*   col   = (const int*)d_in[3];
    const float* efea  = (const float*)d_in[4];
    const float* emb_W = (const float*)d_in[5];
    const float* emb_b = (const float*)d_in[6];
    const float* eW1   = (const float*)d_in[7];
    const float* eb1   = (const float*)d_in[8];
    const float* eW2   = (const float*)d_in[9];
    const float* eb2   = (const float*)d_in[10];
    const float* cW1   = (const float*)d_in[11];
    const float* cb1   = (const float*)d_in[12];
    const float* cW2   = (const float*)d_in[13];
    const float* cb2   = (const float*)d_in[14];
    const float* nW1   = (const float*)d_in[15];
    const float* nb1   = (const float*)d_in[16];
    const float* nW2   = (const float*)d_in[17];
    const float* nb2   = (const float*)d_in[18];

    float* out = (float*)d_out;
    float* xo = out;                 // N*3
    float* ho = out + NN * 3;        // N*64

    // workspace layout (16B-aligned segments)
    char* wsb = (char*)d_ws;
    float* sum_f = (float*)wsb;                                  //    600,000 B
    unsigned short* tmsgb = (unsigned short*)(wsb + 600000);     //  6,400,000 B
    unsigned short* efs = (unsigned short*)(wsb + 7000000);      // 12,800,000 B
    unsigned short* hb  = (unsigned short*)(wsb + 19800000);     //  6,400,000 B
    unsigned short* wsW = (unsigned short*)(wsb + 26200000);     //    122,880 B
    int* deg    = (int*)(wsb + 26322880);                        //    200,000 B
    int* cur    = (int*)(wsb + 26522880);                        //    200,000 B
    int2* rc    = (int2*)(wsb + 26722880);                       //  6,400,000 B
    float* x4   = (float*)(wsb + 33122880);                      //    800,000 B
    int* bsum   = (int*)(wsb + 33922880);                        //        800 B
    int* boff   = (int*)(wsb + 33923680);                        //        800 B

    // zero deg, then fused setup (hist + swizzle + embed + zero + x copies)
    hipMemsetAsync(deg, 0, 200000, stream);
    setup_kernel<<<17917, 256, 0, stream>>>(
        row, deg,
        eW1, eW2, cW1, nW1, nW2, wsW,
        h_in, emb_W, emb_b, ho, hb,
        wsb, x_in, xo, x4);
    // row scan + counting sort
    scanA_kernel<<<200, 256, 0, stream>>>(deg, bsum);
    scanB_kernel<<<1, 256, 0, stream>>>(bsum, boff);
    scanC_kernel<<<200, 256, 0, stream>>>(deg, boff, cur);
    fill_kernel<<<MM / 256, 256, 0, stream>>>(row, col, efea, cur, rc, efs);

    for (int i = 0; i < 2; ++i) {
        const unsigned short* L = wsW + i * 30720;
        edge_mfma_kernel<<<NB_EDGE, 256, 0, stream>>>(
            x4, hb, rc, efs,
            L, L + 10240, L + 14336,
            eb1 + i * 64, eb2 + i * 64, cb1 + i * 64, cW2 + i * 64, cb2 + i,
            sum_f, tmsgb);
        node_mfma_kernel<<<(NN / 16 + 3) / 4, 256, 0, stream>>>(
            xo, x4, ho, hb, sum_f, deg, tmsgb,
            L + 18432, L + 26624, nb1 + i * 64, nb2 + i * 64);
    }
}